// Round 10
// baseline (127.647 us; speedup 1.0000x reference)
//
#include <hip/hip_runtime.h>

typedef _Float16 f16;
typedef _Float16 half8 __attribute__((ext_vector_type(8)));
typedef _Float16 half4v __attribute__((ext_vector_type(4)));
typedef __fp16 fp16x2 __attribute__((ext_vector_type(2)));
typedef float f32x4 __attribute__((ext_vector_type(4)));
typedef float f32x16 __attribute__((ext_vector_type(16)));
typedef unsigned uint4v __attribute__((ext_vector_type(4)));

#define MFMA16(a,b,c) __builtin_amdgcn_mfma_f32_16x16x32_f16((a),(b),(c),0,0,0)
#define MFMA32(a,b,c) __builtin_amdgcn_mfma_f32_32x32x16_f16((a),(b),(c),0,0,0)

__device__ __forceinline__ void gload_lds16(const f16* g, f16* l) {
    __builtin_amdgcn_global_load_lds(
        (const __attribute__((address_space(1))) unsigned int*)g,
        (__attribute__((address_space(3))) unsigned int*)l, 16, 0, 0);
}

__device__ __forceinline__ void plswap(unsigned &a, unsigned &b) {
    asm volatile("v_permlane32_swap_b32 %0, %1" : "+v"(a), "+v"(b));
}

__device__ __forceinline__ unsigned pkexp(float a, float b) {
    return __builtin_bit_cast(unsigned, __builtin_amdgcn_cvt_pkrtz(exp2f(a), exp2f(b)));
}

// ---------------- cast fp32 -> fp16 (vectorized) ----------------
__global__ void cast_f32_to_f16(const float* __restrict__ in, f16* __restrict__ out, int n4) {
    int i = blockIdx.x * blockDim.x + threadIdx.x;
    if (i < n4) {
        float4 v = ((const float4*)in)[i];
        half4v h;
        h.x = (f16)v.x; h.y = (f16)v.y; h.z = (f16)v.z; h.w = (f16)v.w;
        ((half4v*)out)[i] = h;
    }
}

// ---------------- transpose + cast: in[K][N] fp32 -> out[N][K] fp16 ----------------
__global__ void transpose_cast(const float* __restrict__ in, f16* __restrict__ out, int K, int N) {
    __shared__ f16 tile[32][33];
    int n0 = blockIdx.x * 32, k0 = blockIdx.y * 32;
    int tx = threadIdx.x & 31, ty = threadIdx.x >> 5;   // 256 threads = 32x8
    for (int r = ty; r < 32; r += 8)
        tile[r][tx] = (f16)in[(size_t)(k0 + r) * N + (n0 + tx)];
    __syncthreads();
    for (int r = ty; r < 32; r += 8)
        out[(size_t)(n0 + r) * K + (k0 + tx)] = tile[tx][r];
}

// ---------------- GEMM: C[M][N] = A[M][768] * Bt[N][768]^T ----------------
// 3-buffer depth-2 prefetch, counted vmcnt(4), raw s_barrier, XCD swizzle.
// MODE 0: qkv epilogue via LDS roundtrip -> coalesced stores. MODE 1: proj + bias.
template<int MODE>
__global__ __launch_bounds__(256, 3)
void gemm_bt(const f16* __restrict__ A, const f16* __restrict__ Bt,
             f16* __restrict__ qbuf, f16* __restrict__ kbuf, f16* __restrict__ vtbuf,
             float* __restrict__ out, const float* __restrict__ bias)
{
    constexpr int K = 768;
    constexpr int NX = (MODE == 0) ? 18 : 6;   // n-tiles
    constexpr int NWG = NX * 64;
    __shared__ __align__(16) char smem[49152];
    f16* As = (f16*)smem;              // [3][128*32]
    f16* Bs = (f16*)(smem + 24576);    // [3][128*32]
    const int tid  = threadIdx.x;
    const int lane = tid & 63, wave = tid >> 6;
    const int wm = wave >> 1, wn = wave & 1;          // 2x2 waves, 64x64 each
    const int l15 = lane & 15, l4 = lane >> 4;

    // XCD-aware bijective swizzle (NWG % 8 == 0)
    const int bid = blockIdx.x;
    const int swz = (bid & 7) * (NWG / 8) + (bid >> 3);
    const int m0 = (swz / NX) * 128, n0 = (swz % NX) * 128;

    const int srow  = lane >> 2;          // 0..15 row within staging instr
    const int sslot = lane & 3;           // 16B slot within 64B row

    f32x4 acc[4][4] = {};

    #define GSTAGE(buf, kt) do {                                                     \
        _Pragma("unroll")                                                            \
        for (int i = 0; i < 2; ++i) {                                                \
            int rbase = i * 64 + wave * 16;                                          \
            int row = rbase + srow;                                                  \
            gload_lds16(A  + (size_t)(m0 + row) * K + (kt) + sslot * 8, &As[(buf) * 4096 + rbase * 32]); \
            gload_lds16(Bt + (size_t)(n0 + row) * K + (kt) + sslot * 8, &Bs[(buf) * 4096 + rbase * 32]); \
        }                                                                            \
    } while (0)

    GSTAGE(0, 0);
    GSTAGE(1, 32);

    int cur = 0;
    for (int t = 0; t < 24; ++t) {
        if (t < 23) asm volatile("s_waitcnt vmcnt(4)" ::: "memory");
        else        asm volatile("s_waitcnt vmcnt(0)" ::: "memory");
        __builtin_amdgcn_s_barrier();
        if (t < 22) {
            int nb = cur + 2; if (nb >= 3) nb -= 3;
            GSTAGE(nb, (t + 2) * 32);
        }
        half8 af[4], bf[4];
        #pragma unroll
        for (int mi = 0; mi < 4; mi++) af[mi] = *(const half8*)&As[cur*4096 + (wm*64 + mi*16 + l15) * 32 + l4*8];
        #pragma unroll
        for (int ni = 0; ni < 4; ni++) bf[ni] = *(const half8*)&Bs[cur*4096 + (wn*64 + ni*16 + l15) * 32 + l4*8];
        #pragma unroll
        for (int mi = 0; mi < 4; mi++)
            #pragma unroll
            for (int ni = 0; ni < 4; ni++)
                acc[mi][ni] = MFMA16(af[mi], bf[ni], acc[mi][ni]);
        if (++cur >= 3) cur = 0;
    }
    #undef GSTAGE

    if (MODE == 0) {
        // ---- LDS-roundtrip epilogue: coalesced stores ----
        __syncthreads();
        f16* sC = (f16*)smem;          // [128][136]
        const int t3 = n0 / 768;
        const int bb = m0 >> 10;
        const int mo = m0 & 1023;
        const int h0 = (n0 - t3 * 768) >> 6;

        if (t3 < 2) {
            #pragma unroll
            for (int mi = 0; mi < 4; mi++)
                #pragma unroll
                for (int ni = 0; ni < 4; ni++)
                    #pragma unroll
                    for (int r = 0; r < 4; r++) {
                        int row = wm*64 + mi*16 + l4*4 + r;
                        int col = wn*64 + ni*16 + l15;
                        sC[row * 136 + col] = (f16)acc[mi][ni][r];
                    }
            __syncthreads();
            f16* outb = (t3 == 0) ? qbuf : kbuf;
            #pragma unroll
            for (int hc = 0; hc < 2; hc++) {
                f16* base = outb + ((size_t)(bb * 12 + h0 + hc) * 1024 + mo) * 64;
                #pragma unroll
                for (int i = 0; i < 4; i++) {
                    int row = wave * 32 + i * 8 + (lane >> 3);
                    int cc  = (lane & 7) * 8;
                    half8 v = *(const half8*)&sC[row * 136 + hc * 64 + cc];
                    *(half8*)(base + row * 64 + cc) = v;
                }
            }
        } else {
            #pragma unroll
            for (int mi = 0; mi < 4; mi++)
                #pragma unroll
                for (int ni = 0; ni < 4; ni++) {
                    int row0 = wm*64 + mi*16 + l4*4;
                    int col  = wn*64 + ni*16 + l15;
                    half4v pk;
                    #pragma unroll
                    for (int r = 0; r < 4; r++) pk[r] = (f16)acc[mi][ni][r];
                    *(half4v*)&sC[col * 136 + row0] = pk;
                }
            __syncthreads();
            #pragma unroll
            for (int i = 0; i < 8; i++) {
                int col = wave * 32 + i * 4 + (lane >> 4);
                int rc  = (lane & 15) * 8;
                half8 v = *(const half8*)&sC[col * 136 + rc];
                int head = h0 + (col >> 6), dd = col & 63;
                *(half8*)(vtbuf + ((size_t)(bb * 12 + head) * 64 + dd) * 1024 + mo + rc) = v;
            }
        }
    } else {
        #pragma unroll
        for (int mi = 0; mi < 4; mi++)
            #pragma unroll
            for (int ni = 0; ni < 4; ni++)
                #pragma unroll
                for (int r = 0; r < 4; r++) {
                    int gm = m0 + wm*64 + mi*16 + l4*4 + r;
                    int gn = n0 + wn*64 + ni*16 + l15;
                    out[(size_t)gm * 768 + gn] = acc[mi][ni][r] + bias[gn];
                }
    }
}

// ---------------- flash attention: 32x32 MFMA, in-register P (T12), LDS K/V dbuf ----------------
// grid (96 bh, 8 qblk): all q-blocks of a head land on one XCD (96%8==0) -> K/V L2-resident.
__global__ __launch_bounds__(256, 4)
void attn_kernel(const f16* __restrict__ qbuf, const f16* __restrict__ kbuf,
                 const f16* __restrict__ vtbuf, f16* __restrict__ obuf)
{
    __shared__ __align__(16) f16 Ks[2][4096];   // [buf][64 keys][64 d], XOR-swizzled content
    __shared__ __align__(16) f16 Vs[2][4096];   // [buf][64 d][64 keys], XOR-swizzled content
    const int tid = threadIdx.x;
    const int lane = tid & 63, wave = tid >> 6;
    const int bh = blockIdx.x;              // 0..95
    const int b = bh / 12, h = bh % 12;
    const int q0 = blockIdx.y * 128 + wave * 32;
    const int l31 = lane & 31, hi = lane >> 5;
    const int sw0 = (l31 & 7) << 4;

    const f16* Q  = qbuf  + (size_t)bh * 65536;
    const f16* Kp = kbuf  + (size_t)bh * 65536;
    const f16* Vt = vtbuf + (size_t)bh * 65536;

    // Q fragments (B-operand of swapped QK, 32x32x16): col=l31, k=hi*8+j per 16-chunk
    const f16 slh = (f16)(0.125f * 1.44269504089f);
    half8 aq[4];
    #pragma unroll
    for (int c = 0; c < 4; c++) {
        aq[c] = *(const half8*)&Q[(size_t)(q0 + l31) * 64 + c * 16 + hi * 8];
        #pragma unroll
        for (int j = 0; j < 8; j++) aq[c][j] *= slh;
    }

    // staging geometry (pre-swizzled source, linear LDS dest)
    const int srow8 = lane >> 3;
    const int c16   = (lane & 7) ^ srow8;

    f32x16 o0 = {}, o1 = {};
    float lrq = 0.f, mrq = 0.f;

    #define STAGE(buf, kv) do {                                                     \
        _Pragma("unroll")                                                           \
        for (int i = 0; i < 2; ++i) {                                               \
            int rbase = wave * 16 + i * 8;                                          \
            int rl = rbase + srow8;                                                 \
            gload_lds16(Kp + (size_t)((kv) + rl) * 64 + c16 * 8, &Ks[buf][rbase * 64]); \
            gload_lds16(Vt + (size_t)rl * 1024 + (kv) + c16 * 8, &Vs[buf][rbase * 64]); \
        }                                                                           \
    } while (0)

    STAGE(0, 0);
    __syncthreads();

    for (int t = 0; t < 16; ++t) {
        const int cur = t & 1;
        if (t < 15) STAGE(cur ^ 1, (t + 1) * 64);

        const char* Kb = (const char*)&Ks[cur][0];
        const char* Vb = (const char*)&Vs[cur][0];

        // swapped QK (32x32x16): st = S^T[key][q] - mrq, log2 domain
        f32x16 st0, st1;
        #pragma unroll
        for (int j = 0; j < 16; j++) { st0[j] = -mrq; st1[j] = -mrq; }
        __builtin_amdgcn_s_setprio(1);
        #pragma unroll
        for (int c = 0; c < 4; c++) {
            int koff = (c * 32 + hi * 16) ^ sw0;
            half8 k0 = *(const half8*)(Kb + l31 * 128 + koff);
            half8 k1 = *(const half8*)(Kb + (32 + l31) * 128 + koff);
            st0 = MFMA32(k0, aq[c], st0);
            st1 = MFMA32(k1, aq[c], st1);
        }
        __builtin_amdgcn_s_setprio(0);

        // relative row max (lane holds 32 keys for query l31; complement in lane^32)
        float m16 = st0[0];
        #pragma unroll
        for (int j = 1; j < 16; j++) m16 = fmaxf(m16, st0[j]);
        #pragma unroll
        for (int j = 0; j < 16; j++) m16 = fmaxf(m16, st1[j]);
        m16 = fmaxf(m16, __shfl_xor(m16, 32));

        // defer-max (T13)
        if (!__all(m16 <= 11.0f)) {
            float d = fmaxf(m16, 0.f);
            float alpha = exp2f(-d);
            mrq += d;
            #pragma unroll
            for (int j = 0; j < 16; j++) { st0[j] -= d; st1[j] -= d; }
            lrq *= alpha;
            #pragma unroll
            for (int reg = 0; reg < 16; reg++) {
                float a = __shfl(alpha, (reg & 3) + 8 * (reg >> 2) + 4 * hi);
                o0[reg] *= a; o1[reg] *= a;
            }
        }

        // P = exp2(st) -> f16 pairs -> permlane32_swap -> PV A-fragments (in registers).
        // pa[kc][j] = P[q=l31][key = kc*16 + hi*8 + j]
        float rs = 0.f;
        #pragma unroll
        for (int j = 0; j < 16; j++) rs += exp2f(st0[j]);   // folded below via pkexp anyway
        rs = 0.f;
        half8 pa[4];
        #pragma unroll
        for (int tile = 0; tile < 2; tile++) {
            const f32x16& sv = tile ? st1 : st0;
            #pragma unroll
            for (int half16 = 0; half16 < 2; half16++) {   // regs 0-7 vs 8-15 -> pa[2*tile+half16... ]
                int rb = half16 * 8;
                unsigned A1 = pkexp(sv[rb+0], sv[rb+1]);
                unsigned B1 = pkexp(sv[rb+4], sv[rb+5]);
                unsigned A2 = pkexp(sv[rb+2], sv[rb+3]);
                unsigned B2 = pkexp(sv[rb+6], sv[rb+7]);
                plswap(A1, B1);
                plswap(A2, B2);
                uint4v w = {A1, A2, B1, B2};
                pa[tile * 2 + half16] = __builtin_bit_cast(half8, w);
            }
            #pragma unroll
            for (int j = 0; j < 16; j++) rs += exp2f(sv[j]);
        }
        rs += __shfl_xor(rs, 32);
        lrq += rs;

        // PV (32x32x16): A = pa (registers), B = V^T frags from LDS
        __builtin_amdgcn_s_setprio(1);
        #pragma unroll
        for (int kc = 0; kc < 4; kc++) {
            int koff = (kc * 32 + hi * 16) ^ sw0;
            half8 v0 = *(const half8*)(Vb + l31 * 128 + koff);
            half8 v1 = *(const half8*)(Vb + (32 + l31) * 128 + koff);
            o0 = MFMA32(pa[kc], v0, o0);
            o1 = MFMA32(pa[kc], v1, o1);
        }
        __builtin_amdgcn_s_setprio(0);

        __syncthreads();   // drains vmcnt (staged tile ready) + guards buffer reuse
    }
    #undef STAGE

    // epilogue: redistribute 1/lrq (at q=l31) to O's reg-mapped rows
    float rq = 1.0f / lrq;
    f16* Op = obuf + (size_t)b * 1024 * 768 + h * 64;
    #pragma unroll
    for (int reg = 0; reg < 16; reg++) {
        int qrow = (reg & 3) + 8 * (reg >> 2) + 4 * hi;
        float inv = __shfl(rq, qrow);
        size_t base = (size_t)(q0 + qrow) * 768;
        Op[base + l31]      = (f16)(o0[reg] * inv);
        Op[base + 32 + l31] = (f16)(o1[reg] * inv);
    }
}

extern "C" void kernel_launch(void* const* d_in, const int* in_sizes, int n_in,
                              void* d_out, int out_size, void* d_ws, size_t ws_size,
                              hipStream_t stream) {
    const float* x      = (const float*)d_in[0];
    const float* w_qkv  = (const float*)d_in[1];
    const float* w_proj = (const float*)d_in[2];
    const float* b_proj = (const float*)d_in[3];
    float* out = (float*)d_out;
    char* ws = (char*)d_ws;

    f16* x_h      = (f16*)(ws + 0);
    f16* w_qkv_t  = (f16*)(ws + 12582912);
    f16* w_proj_t = (f16*)(ws + 16121856);
    f16* qb       = (f16*)(ws + 17301504);
    f16* kb       = (f16*)(ws + 29884416);
    f16* vtb      = (f16*)(ws + 42467328);
    f16* ob       = (f16*)(ws + 55050240);

    cast_f32_to_f16<<<dim3(6144), dim3(256), 0, stream>>>(x, x_h, 6291456 / 4);
    transpose_cast<<<dim3(2304 / 32, 768 / 32), dim3(256), 0, stream>>>(w_qkv, w_qkv_t, 768, 2304);
    transpose_cast<<<dim3(768 / 32, 768 / 32), dim3(256), 0, stream>>>(w_proj, w_proj_t, 768, 768);
    gemm_bt<0><<<dim3(18 * 64), dim3(256), 0, stream>>>(
        x_h, w_qkv_t, qb, kb, vtb, nullptr, nullptr);
    attn_kernel<<<dim3(96, 8), dim3(256), 0, stream>>>(qb, kb, vtb, ob);
    gemm_bt<1><<<dim3(6 * 64), dim3(256), 0, stream>>>(
        ob, w_proj_t, nullptr, nullptr, nullptr, out, b_proj);
}